// Round 1
// baseline (16898.061 us; speedup 1.0000x reference)
//
#include <hip/hip_runtime.h>
#include <stdint.h>
#include <stddef.h>

// Persistent 2-layer LSTM for MI355X (gfx950).
// B=128,T=512,D=128,H=512. 4 clusters x 64 blocks; block owns 8 h-cols of each
// layer; weights register-resident as MFMA B-fragments; one flag-sync per step.

typedef __attribute__((ext_vector_type(8))) short short8;
typedef __attribute__((ext_vector_type(4))) float f32x4;

#define DEV static __device__ __forceinline__

constexpr int TSEQ = 512;
constexpr int DIN  = 128;
constexpr int HDIM = 512;
constexpr int CLUSTERS = 4;
constexpr int BB   = 32;   // batch rows per cluster
constexpr int COLS = 8;    // h-cols per block (per layer)
constexpr int S1H  = 10;   // layer-1 K-steps (of 32) per K-half: total 20 (4 from x, 16 from h1)
constexpr int S2H  = 16;   // layer-2 K-steps per K-half: total 32 (16 out1, 16 h2)

DEV unsigned short f2bf(float f) {
  unsigned u = __float_as_uint(f);
  u += 0x7fffu + ((u >> 16) & 1u);   // RNE
  return (unsigned short)(u >> 16);
}
DEV short8 pack8(float4 a, float4 b) {
  short8 r;
  r[0] = (short)f2bf(a.x); r[1] = (short)f2bf(a.y);
  r[2] = (short)f2bf(a.z); r[3] = (short)f2bf(a.w);
  r[4] = (short)f2bf(b.x); r[5] = (short)f2bf(b.y);
  r[6] = (short)f2bf(b.z); r[7] = (short)f2bf(b.w);
  return r;
}
DEV f32x4 mfma16(short8 a, short8 b, f32x4 c) {
  return __builtin_amdgcn_mfma_f32_16x16x32_bf16(a, b, c, 0, 0, 0);
}
DEV float sigf(float v) { return 1.f / (1.f + __expf(-v)); }
DEV float tanh_(float v) {
  v = fminf(20.f, fmaxf(-20.f, v));
  float e = __expf(2.f * v);
  return (e - 1.f) / (e + 1.f);
}

__global__ void zero_ws(unsigned* p, int n) {
  int i = blockIdx.x * 256 + threadIdx.x;
  if (i < n) p[i] = 0u;
}

// reduction scratch layout: [kh(2)][mh(2)][m(16)][n(33 padded)]
#define RED(khh, mhh, mm, nn) (((((khh)*2 + (mhh))*16 + (mm))*33) + (nn))

__global__ __launch_bounds__(256, 1) void lstm_persist(
    const float* __restrict__ x,
    const float* __restrict__ Wih1, const float* __restrict__ Whh1,
    const float* __restrict__ bih1, const float* __restrict__ bhh1,
    const float* __restrict__ Wih2, const float* __restrict__ Whh2,
    const float* __restrict__ bih2, const float* __restrict__ bhh2,
    float* __restrict__ out,
    unsigned short* __restrict__ buf1,   // [2][CLUSTERS][BB][HDIM] bf16 (h1/out1)
    unsigned short* __restrict__ buf2,   // [2][CLUSTERS][BB][HDIM] bf16 (h2)
    unsigned* __restrict__ flags)        // [CLUSTERS][64]
{
  __shared__ float red1[4 * 16 * 33];
  __shared__ float red2[4 * 16 * 33];
  __shared__ float bias1s[32], bias2s[32];

  const int tid  = threadIdx.x;
  const int lane = tid & 63;
  const int lm   = lane & 15;
  const int lq   = lane >> 4;
  const int wave = tid >> 6;
  const int mh   = wave & 1;   // M-half (batch rows 16*mh..+16)
  const int kh   = wave >> 1;  // K-half

  // XCD-aware swizzle: cluster c on XCDs {2c,2c+1} (assumes blockIdx%8 -> XCD;
  // wrong mapping only costs locality, never correctness).
  const int bid = blockIdx.x;
  const int xcd = bid & 7;
  const int cluster = xcd >> 1;
  const int j = ((bid >> 3) << 1) | (xcd & 1);   // 0..63: column-group in cluster
  const int cb = cluster * BB;                   // global batch base

  // ---- load weight fragments into registers (persistent across all steps) ----
  // tile row r = g*8+ci (g=gate i,f,g,o ; ci=col within block) -> gate row g*H + j*8+ci
  short8 wf1[2][S1H];
  short8 wf2[2][S2H];
  {
    #pragma unroll
    for (int nh = 0; nh < 2; ++nh) {
      const int r  = nh * 16 + lm;
      const int g  = r >> 3, ci = r & 7;
      const int gr = g * HDIM + j * COLS + ci;
      #pragma unroll
      for (int sl = 0; sl < S1H; ++sl) {
        const int k0 = (kh * S1H + sl) * 32 + 8 * lq;   // 0..639
        const float* src = (k0 < DIN) ? (Wih1 + (size_t)gr * DIN + k0)
                                      : (Whh1 + (size_t)gr * HDIM + (k0 - DIN));
        wf1[nh][sl] = pack8(*(const float4*)src, *(const float4*)(src + 4));
      }
      #pragma unroll
      for (int sl = 0; sl < S2H; ++sl) {
        const int k0 = (kh * S2H + sl) * 32 + 8 * lq;   // 0..1023
        const float* src = (k0 < HDIM) ? (Wih2 + (size_t)gr * HDIM + k0)
                                       : (Whh2 + (size_t)gr * HDIM + (k0 - HDIM));
        wf2[nh][sl] = pack8(*(const float4*)src, *(const float4*)(src + 4));
      }
    }
  }
  if (tid < 32) {
    const int g = tid >> 3, ci = tid & 7;
    const int gr = g * HDIM + j * COLS + ci;
    bias1s[tid] = bih1[gr] + bhh1[gr];
    bias2s[tid] = bih2[gr] + bhh2[gr];
  }
  __syncthreads();

  // pickup mapping: one thread per (batch row, h-col)
  const int pmh  = tid >> 7;
  const int pm   = (tid >> 3) & 15;
  const int pci  = tid & 7;
  const int prow = pmh * 16 + pm;          // cluster-local batch row
  const int pcol = j * COLS + pci;         // h column 0..511

  float c1 = 0.f, c2 = 0.f;

  const int am = mh * 16 + lm;             // A-fragment batch row (cluster-local)

  for (int it = 0; it <= TSEQ; ++it) {
    // ---- wait: all cluster blocks finished iteration it-1 ----
    if (it > 0) {
      if (tid < 64) {
        const unsigned* fl = flags + cluster * 64;
        while (true) {
          unsigned v = __hip_atomic_load(fl + tid, __ATOMIC_RELAXED,
                                         __HIP_MEMORY_SCOPE_AGENT);
          if (__all((int)(v >= (unsigned)it))) break;
        }
      }
      __syncthreads();
      __threadfence();   // acquire: make peers' h-publishes visible
    }

    f32x4 a10 = {0.f, 0.f, 0.f, 0.f};
    f32x4 a11 = a10, a20 = a10, a21 = a10;

    // ---- layer 1, step t=it : gates = [x_t | h1_{t-1}] . W1^T ----
    if (it < TSEQ) {
      const unsigned short* h1r =
          buf1 + (size_t)((((it + 1) & 1) * CLUSTERS + cluster) * BB) * HDIM;
      #pragma unroll
      for (int sl = 0; sl < S1H; ++sl) {
        const int s = kh * S1H + sl;
        short8 a;
        if (s < 4) {  // x part (only kh==0 waves)
          const float* xp = x + ((size_t)(cb + am) * TSEQ + it) * DIN + s * 32 + 8 * lq;
          a = pack8(*(const float4*)xp, *(const float4*)(xp + 4));
        } else {      // h1_{t-1} part
          a = *(const short8*)(h1r + (size_t)am * HDIM + (s - 4) * 32 + 8 * lq);
        }
        a10 = mfma16(a, wf1[0][sl], a10);
        a11 = mfma16(a, wf1[1][sl], a11);
      }
    }
    // ---- layer 2, step t2=it-1 : gates = [out1_{t2} | h2_{t2-1}] . W2^T ----
    if (it >= 1) {
      const unsigned short* o1r =
          buf1 + (size_t)((((it + 1) & 1) * CLUSTERS + cluster) * BB) * HDIM;
      const unsigned short* h2r =
          buf2 + (size_t)(((it & 1) * CLUSTERS + cluster) * BB) * HDIM;
      const unsigned short* src = kh ? h2r : o1r;   // kh0: K 0..511 ; kh1: K 512..1023
      #pragma unroll
      for (int sl = 0; sl < S2H; ++sl) {
        short8 a = *(const short8*)(src + (size_t)am * HDIM + sl * 32 + 8 * lq);
        a20 = mfma16(a, wf2[0][sl], a20);
        a21 = mfma16(a, wf2[1][sl], a21);
      }
    }

    // ---- K-half partial reduction through LDS ----
    if (it < TSEQ) {
      #pragma unroll
      for (int r = 0; r < 4; ++r) {
        red1[RED(kh, mh, lq * 4 + r, lm)]      = a10[r];
        red1[RED(kh, mh, lq * 4 + r, 16 + lm)] = a11[r];
      }
    }
    if (it >= 1) {
      #pragma unroll
      for (int r = 0; r < 4; ++r) {
        red2[RED(kh, mh, lq * 4 + r, lm)]      = a20[r];
        red2[RED(kh, mh, lq * 4 + r, 16 + lm)] = a21[r];
      }
    }
    __syncthreads();

    // ---- pickup: gate activations + state update + publish ----
    if (it < TSEQ) {
      float p[4];
      #pragma unroll
      for (int gi = 0; gi < 4; ++gi) {
        const int n = gi * 8 + pci;
        p[gi] = red1[RED(0, pmh, pm, n)] + red1[RED(1, pmh, pm, n)] + bias1s[n];
      }
      const float i_ = sigf(p[0]), f_ = sigf(p[1]);
      const float g_ = tanh_(p[2]), o_ = sigf(p[3]);
      c1 = f_ * c1 + i_ * g_;
      const float h1v = o_ * tanh_(c1);
      unsigned short* w =
          buf1 + (size_t)(((it & 1) * CLUSTERS + cluster) * BB) * HDIM;
      w[(size_t)prow * HDIM + pcol] = f2bf(h1v);
    }
    if (it >= 1) {
      float p[4];
      #pragma unroll
      for (int gi = 0; gi < 4; ++gi) {
        const int n = gi * 8 + pci;
        p[gi] = red2[RED(0, pmh, pm, n)] + red2[RED(1, pmh, pm, n)] + bias2s[n];
      }
      const float i_ = sigf(p[0]), f_ = sigf(p[1]);
      const float g_ = tanh_(p[2]), o_ = sigf(p[3]);
      c2 = f_ * c2 + i_ * g_;
      const float h2v = o_ * tanh_(c2);
      if (it < TSEQ) {
        unsigned short* w =
            buf2 + (size_t)((((it + 1) & 1) * CLUSTERS + cluster) * BB) * HDIM;
        w[(size_t)prow * HDIM + pcol] = f2bf(h2v);
      } else {
        // final states after t=511 -> hT, cT (fp32)
        const int b = cb + prow;
        out[(size_t)b * HDIM + pcol] = h2v;
        out[(size_t)128 * HDIM + (size_t)b * HDIM + pcol] = c2;
      }
    }
    __syncthreads();

    // ---- publish flag (release) ----
    if (tid == 0 && it < TSEQ) {
      __threadfence();
      __hip_atomic_store(flags + cluster * 64 + j, (unsigned)(it + 1),
                         __ATOMIC_RELEASE, __HIP_MEMORY_SCOPE_AGENT);
    }
  }
}

extern "C" void kernel_launch(void* const* d_in, const int* in_sizes, int n_in,
                              void* d_out, int out_size, void* d_ws, size_t ws_size,
                              hipStream_t stream) {
  const float* x    = (const float*)d_in[0];
  const float* Wih1 = (const float*)d_in[1];
  const float* Whh1 = (const float*)d_in[2];
  const float* bih1 = (const float*)d_in[3];
  const float* bhh1 = (const float*)d_in[4];
  const float* Wih2 = (const float*)d_in[5];
  const float* Whh2 = (const float*)d_in[6];
  const float* bih2 = (const float*)d_in[7];
  const float* bhh2 = (const float*)d_in[8];
  float* out = (float*)d_out;

  const size_t bufElems = (size_t)2 * CLUSTERS * BB * HDIM;   // 131072 ushorts
  unsigned short* buf1 = (unsigned short*)d_ws;
  unsigned short* buf2 = buf1 + bufElems;
  unsigned* flags = (unsigned*)(buf2 + bufElems);

  const int nzero = (int)((bufElems * 2 * 2 + CLUSTERS * 64 * 4) / 4);  // words
  zero_ws<<<(nzero + 255) / 256, 256, 0, stream>>>((unsigned*)d_ws, nzero);
  lstm_persist<<<256, 256, 0, stream>>>(x, Wih1, Whh1, bih1, bhh1,
                                        Wih2, Whh2, bih2, bhh2,
                                        out, buf1, buf2, flags);
}

// Round 2
// 13654.720 us; speedup vs baseline: 1.2375x; 1.2375x over previous
//
#include <hip/hip_runtime.h>
#include <stdint.h>
#include <stddef.h>

// Persistent 2-layer LSTM, V2: single-XCD clusters + backoff barrier + LDS A-staging.
// B=128,T=512,D=128,H=512. 8 clusters (1/XCD) x 32 blocks; block owns 16 h-cols
// of both layers; weights register-resident; 4 waves = 4 K-quarters.

typedef __attribute__((ext_vector_type(8))) short short8;
typedef __attribute__((ext_vector_type(4))) float f32x4;

#define DEV static __device__ __forceinline__

constexpr int TSEQ = 512;
constexpr int DIN  = 128;
constexpr int HDIM = 512;
constexpr int NCL  = 8;    // clusters, one per XCD (bid&7 heuristic; perf-only)
constexpr int BB   = 16;   // batch rows per cluster
constexpr int NJ   = 32;   // blocks per cluster
constexpr int COLS = 16;   // h-cols per block

DEV unsigned short f2bf(float f) {
  unsigned u = __float_as_uint(f);
  u += 0x7fffu + ((u >> 16) & 1u);   // RNE
  return (unsigned short)(u >> 16);
}
DEV short8 pack8(float4 a, float4 b) {
  short8 r;
  r[0] = (short)f2bf(a.x); r[1] = (short)f2bf(a.y);
  r[2] = (short)f2bf(a.z); r[3] = (short)f2bf(a.w);
  r[4] = (short)f2bf(b.x); r[5] = (short)f2bf(b.y);
  r[6] = (short)f2bf(b.z); r[7] = (short)f2bf(b.w);
  return r;
}
DEV f32x4 mfma16(short8 a, short8 b, f32x4 c) {
  return __builtin_amdgcn_mfma_f32_16x16x32_bf16(a, b, c, 0, 0, 0);
}
DEV float sigf(float v) { return 1.f / (1.f + __expf(-v)); }
DEV float tanh_(float v) {
  v = fminf(20.f, fmaxf(-20.f, v));
  float e = __expf(2.f * v);
  return (e - 1.f) / (e + 1.f);
}

__global__ void zero_ws(unsigned* p, int n) {
  int i = blockIdx.x * 256 + threadIdx.x;
  if (i < n) p[i] = 0u;
}

// LDS A-slab element-index swizzle: idx ^ ((row&7)<<3)  (== byte ^ (row&7)<<4)
#define SWZ(row, idx) ((idx) ^ (((row) & 7) << 3))

__global__ __launch_bounds__(256, 1) void lstm_persist(
    const float* __restrict__ x,
    const float* __restrict__ Wih1, const float* __restrict__ Whh1,
    const float* __restrict__ bih1, const float* __restrict__ bhh1,
    const float* __restrict__ Wih2, const float* __restrict__ Whh2,
    const float* __restrict__ bih2, const float* __restrict__ bhh2,
    float* __restrict__ out,
    unsigned short* __restrict__ buf1,   // [2][NCL][BB][HDIM] bf16 (h1/out1)
    unsigned short* __restrict__ buf2,   // [2][NCL][BB][HDIM] bf16 (h2)
    unsigned* __restrict__ flags)        // [NCL][64] (first NJ used)
{
  __shared__ short xs [16 * DIN];    // x_t slab (bf16)
  __shared__ short h1s[16 * HDIM];   // h1_{t-1} slab
  __shared__ short h2s[16 * HDIM];   // h2_{t-2} slab
  __shared__ float red1[4 * 16 * 66];
  __shared__ float red2[4 * 16 * 66];
  __shared__ float bias1s[64], bias2s[64];

  const int tid  = threadIdx.x;
  const int lane = tid & 63;
  const int lm   = lane & 15;   // A row / C col index
  const int lq   = lane >> 4;   // k-octet / C row group
  const int kq   = tid >> 6;    // wave = K-quarter

  const int bid     = blockIdx.x;
  const int cluster = bid & 7;        // XCD (heuristic)
  const int j       = bid >> 3;       // 0..31 col-group within cluster
  const int cb      = cluster * BB;   // global batch base

  // ---- persistent register weights: B-fragments, n = lane&15 -> gate row ----
  short8 wf1[4][5];   // layer1: K=640 -> 20 K-steps, 5 per wave, x4 gates
  short8 wf2[4][8];   // layer2: K=1024 -> 32 K-steps, 8 per wave, x4 gates
  #pragma unroll
  for (int g = 0; g < 4; ++g) {
    const int gr = g * HDIM + j * COLS + lm;
    #pragma unroll
    for (int sl = 0; sl < 5; ++sl) {
      const int k0 = (kq * 5 + sl) * 32 + 8 * lq;          // 0..639
      const float* src = (k0 < DIN) ? (Wih1 + (size_t)gr * DIN + k0)
                                    : (Whh1 + (size_t)gr * HDIM + (k0 - DIN));
      wf1[g][sl] = pack8(*(const float4*)src, *(const float4*)(src + 4));
    }
    #pragma unroll
    for (int sl = 0; sl < 8; ++sl) {
      const int k0 = (kq * 8 + sl) * 32 + 8 * lq;          // 0..1023
      const float* src = (k0 < HDIM) ? (Wih2 + (size_t)gr * HDIM + k0)
                                     : (Whh2 + (size_t)gr * HDIM + (k0 - HDIM));
      wf2[g][sl] = pack8(*(const float4*)src, *(const float4*)(src + 4));
    }
  }
  if (tid < 64) {
    const int g = tid >> 4, nn = tid & 15;
    const int gr = g * HDIM + j * COLS + nn;
    bias1s[tid] = bih1[gr] + bhh1[gr];
    bias2s[tid] = bih2[gr] + bhh2[gr];
  }

  // pickup: thread = (batch row pm, col pnn); owns c1,c2 across all steps
  const int pm = tid >> 4, pnn = tid & 15;
  float c1 = 0.f, c2 = 0.f;

  for (int it = 0; it <= TSEQ; ++it) {
    // ---- barrier: all cluster blocks done with iteration it-1 ----
    if (it > 0) {
      if (tid < NJ) {
        const unsigned* fl = flags + cluster * 64 + tid;
        while (__hip_atomic_load(fl, __ATOMIC_RELAXED,
                                 __HIP_MEMORY_SCOPE_AGENT) < (unsigned)it)
          __builtin_amdgcn_s_sleep(2);
      }
      __syncthreads();
      __threadfence();   // acquire: peers' h publishes
    }

    // ---- stage A-slabs into swizzled LDS ----
    const unsigned short* h1r =
        buf1 + (size_t)(((it + 1) & 1) * NCL + cluster) * BB * HDIM;  // h1_{it-1}
    const unsigned short* h2r =
        buf2 + (size_t)((it & 1) * NCL + cluster) * BB * HDIM;        // h2_{it-2}
    if (it < TSEQ) {   // x_t (fp32 -> bf16); guarded: t=TSEQ would read OOB
      const int row = tid >> 4, kc = tid & 15;
      const float* xp = x + ((size_t)(cb + row) * TSEQ + it) * DIN + kc * 8;
      *(short8*)(&xs[SWZ(row, row * DIN + kc * 8)]) =
          pack8(*(const float4*)xp, *(const float4*)(xp + 4));
    }
    #pragma unroll
    for (int ci = 0; ci < 4; ++ci) {
      const int c = ci * 256 + tid;
      const int row = c >> 6, kc = c & 63;
      *(short8*)(&h1s[SWZ(row, row * HDIM + kc * 8)]) =
          *(const short8*)(h1r + (size_t)row * HDIM + kc * 8);
    }
    #pragma unroll
    for (int ci = 0; ci < 4; ++ci) {
      const int c = ci * 256 + tid;
      const int row = c >> 6, kc = c & 63;
      *(short8*)(&h2s[SWZ(row, row * HDIM + kc * 8)]) =
          *(const short8*)(h2r + (size_t)row * HDIM + kc * 8);
    }
    __syncthreads();

    // ---- MFMA: wave kq does its K-quarter, all 4 gate N-tiles ----
    f32x4 z = {0.f, 0.f, 0.f, 0.f};
    f32x4 acc1[4] = {z, z, z, z};
    f32x4 acc2[4] = {z, z, z, z};
    if (it < TSEQ) {
      #pragma unroll
      for (int sl = 0; sl < 5; ++sl) {
        const int s = kq * 5 + sl;       // global K-step, K = [x(4) | h1(16)]
        short8 a;
        if (s < 4)
          a = *(const short8*)(&xs[SWZ(lm, lm * DIN + s * 32 + 8 * lq)]);
        else
          a = *(const short8*)(&h1s[SWZ(lm, lm * HDIM + (s - 4) * 32 + 8 * lq)]);
        #pragma unroll
        for (int g = 0; g < 4; ++g) acc1[g] = mfma16(a, wf1[g][sl], acc1[g]);
      }
    }
    if (it >= 1) {
      #pragma unroll
      for (int sl = 0; sl < 8; ++sl) {
        const int s2 = kq * 8 + sl;      // K = [out1(16) | h2(16)]
        short8 a;
        if (s2 < 16)
          a = *(const short8*)(&h1s[SWZ(lm, lm * HDIM + s2 * 32 + 8 * lq)]);
        else
          a = *(const short8*)(&h2s[SWZ(lm, lm * HDIM + (s2 - 16) * 32 + 8 * lq)]);
        #pragma unroll
        for (int g = 0; g < 4; ++g) acc2[g] = mfma16(a, wf2[g][sl], acc2[g]);
      }
    }
    // C layout: col = lane&15 (gate row), row = lq*4+r (batch row)
    if (it < TSEQ) {
      #pragma unroll
      for (int g = 0; g < 4; ++g)
        #pragma unroll
        for (int r = 0; r < 4; ++r)
          red1[(kq * 16 + lq * 4 + r) * 66 + g * 16 + lm] = acc1[g][r];
    }
    if (it >= 1) {
      #pragma unroll
      for (int g = 0; g < 4; ++g)
        #pragma unroll
        for (int r = 0; r < 4; ++r)
          red2[(kq * 16 + lq * 4 + r) * 66 + g * 16 + lm] = acc2[g][r];
    }
    __syncthreads();

    // ---- pickup: K-quarter reduce + gates + state + publish ----
    if (it < TSEQ) {
      float p[4];
      #pragma unroll
      for (int g = 0; g < 4; ++g) {
        float v = bias1s[g * 16 + pnn];
        #pragma unroll
        for (int q = 0; q < 4; ++q) v += red1[(q * 16 + pm) * 66 + g * 16 + pnn];
        p[g] = v;
      }
      const float i_ = sigf(p[0]), f_ = sigf(p[1]);
      const float g_ = tanh_(p[2]), o_ = sigf(p[3]);
      c1 = f_ * c1 + i_ * g_;
      const float h1v = o_ * tanh_(c1);
      unsigned short* w = buf1 + (size_t)((it & 1) * NCL + cluster) * BB * HDIM;
      w[pm * HDIM + j * COLS + pnn] = f2bf(h1v);
    }
    if (it >= 1) {
      float p[4];
      #pragma unroll
      for (int g = 0; g < 4; ++g) {
        float v = bias2s[g * 16 + pnn];
        #pragma unroll
        for (int q = 0; q < 4; ++q) v += red2[(q * 16 + pm) * 66 + g * 16 + pnn];
        p[g] = v;
      }
      const float i_ = sigf(p[0]), f_ = sigf(p[1]);
      const float g_ = tanh_(p[2]), o_ = sigf(p[3]);
      c2 = f_ * c2 + i_ * g_;
      const float h2v = o_ * tanh_(c2);
      if (it < TSEQ) {
        unsigned short* w =
            buf2 + (size_t)(((it + 1) & 1) * NCL + cluster) * BB * HDIM;
        w[pm * HDIM + j * COLS + pnn] = f2bf(h2v);
      } else {
        const int b = cb + pm;                       // final states (t = 511)
        out[(size_t)b * HDIM + j * COLS + pnn] = h2v;
        out[(size_t)128 * HDIM + (size_t)b * HDIM + j * COLS + pnn] = c2;
      }
    }
    __syncthreads();

    // ---- release flag ----
    if (tid == 0 && it < TSEQ) {
      __threadfence();
      __hip_atomic_store(flags + cluster * 64 + j, (unsigned)(it + 1),
                         __ATOMIC_RELEASE, __HIP_MEMORY_SCOPE_AGENT);
    }
  }
}

extern "C" void kernel_launch(void* const* d_in, const int* in_sizes, int n_in,
                              void* d_out, int out_size, void* d_ws, size_t ws_size,
                              hipStream_t stream) {
  const float* x    = (const float*)d_in[0];
  const float* Wih1 = (const float*)d_in[1];
  const float* Whh1 = (const float*)d_in[2];
  const float* bih1 = (const float*)d_in[3];
  const float* bhh1 = (const float*)d_in[4];
  const float* Wih2 = (const float*)d_in[5];
  const float* Whh2 = (const float*)d_in[6];
  const float* bih2 = (const float*)d_in[7];
  const float* bhh2 = (const float*)d_in[8];
  float* out = (float*)d_out;

  const size_t bufElems = (size_t)2 * NCL * BB * HDIM;   // 131072 ushorts each
  unsigned short* buf1 = (unsigned short*)d_ws;
  unsigned short* buf2 = buf1 + bufElems;
  unsigned* flags = (unsigned*)(buf2 + bufElems);

  const int nzero = (int)((bufElems * 2 * 2 + NCL * 64 * 4) / 4);   // u32 words
  zero_ws<<<(nzero + 255) / 256, 256, 0, stream>>>((unsigned*)d_ws, nzero);
  lstm_persist<<<256, 256, 0, stream>>>(x, Wih1, Whh1, bih1, bhh1,
                                        Wih2, Whh2, bih2, bhh2,
                                        out, buf1, buf2, flags);
}

// Round 3
// 2254.332 us; speedup vs baseline: 7.4958x; 6.0571x over previous
//
#include <hip/hip_runtime.h>
#include <stdint.h>
#include <stddef.h>

// Persistent 2-layer LSTM, V3: fence-free cross-block comm via agent-scope
// relaxed atomics (cache-bypassing), counter barrier, no __threadfence.
// B=128,T=512,D=128,H=512. 8 clusters x 32 blocks; block owns 16 h-cols of
// both layers; weights register-resident; 4 waves = 4 K-quarters.

typedef __attribute__((ext_vector_type(8))) short short8;
typedef __attribute__((ext_vector_type(4))) float f32x4;

#define DEV static __device__ __forceinline__
#define SCOPE_AGENT __HIP_MEMORY_SCOPE_AGENT

constexpr int TSEQ = 512;
constexpr int DIN  = 128;
constexpr int HDIM = 512;
constexpr int NCL  = 8;    // clusters (bid&7 -> XCD heuristic; perf-only)
constexpr int BB   = 16;   // batch rows per cluster
constexpr int NJ   = 32;   // blocks per cluster
constexpr int COLS = 16;   // h-cols per block

DEV unsigned short f2bf(float f) {
  unsigned u = __float_as_uint(f);
  u += 0x7fffu + ((u >> 16) & 1u);   // RNE
  return (unsigned short)(u >> 16);
}
DEV short8 pack8(float4 a, float4 b) {
  short8 r;
  r[0] = (short)f2bf(a.x); r[1] = (short)f2bf(a.y);
  r[2] = (short)f2bf(a.z); r[3] = (short)f2bf(a.w);
  r[4] = (short)f2bf(b.x); r[5] = (short)f2bf(b.y);
  r[6] = (short)f2bf(b.z); r[7] = (short)f2bf(b.w);
  return r;
}
DEV f32x4 mfma16(short8 a, short8 b, f32x4 c) {
  return __builtin_amdgcn_mfma_f32_16x16x32_bf16(a, b, c, 0, 0, 0);
}
DEV float sigf(float v) { return 1.f / (1.f + __expf(-v)); }
DEV float tanh_(float v) {
  v = fminf(20.f, fmaxf(-20.f, v));
  float e = __expf(2.f * v);
  return (e - 1.f) / (e + 1.f);
}

__global__ void zero_ws(unsigned* p, int n) {
  int i = blockIdx.x * 256 + threadIdx.x;
  if (i < n)
    __hip_atomic_store(p + i, 0u, __ATOMIC_RELAXED, SCOPE_AGENT);
}

// LDS slab swizzle on short-index: byte ^ ((row&15)<<4)
#define SWZ(row, idx) ((idx) ^ (((row) & 15) << 3))

__global__ __launch_bounds__(256, 1) void lstm_persist(
    const float* __restrict__ x,
    const float* __restrict__ Wih1, const float* __restrict__ Whh1,
    const float* __restrict__ bih1, const float* __restrict__ bhh1,
    const float* __restrict__ Wih2, const float* __restrict__ Whh2,
    const float* __restrict__ bih2, const float* __restrict__ bhh2,
    float* __restrict__ out,
    unsigned short* __restrict__ buf1,   // [2][NCL][BB][HDIM] bf16 (h1/out1)
    unsigned short* __restrict__ buf2,   // [2][NCL][BB][HDIM] bf16 (h2)
    unsigned* __restrict__ flags)        // [NCL] step counters
{
  __shared__ short xs [16 * DIN];    // x_t slab (bf16, swizzled)
  __shared__ short h1s[16 * HDIM];   // h1_{t-1} slab
  __shared__ short h2s[16 * HDIM];   // h2_{t-2} slab
  __shared__ float red1[4 * 16 * 66];
  __shared__ float red2[4 * 16 * 66];
  __shared__ float bias1s[64], bias2s[64];

  const int tid  = threadIdx.x;
  const int lane = tid & 63;
  const int lm   = lane & 15;   // A row / C col index
  const int lq   = lane >> 4;   // k-octet / C row group
  const int kq   = tid >> 6;    // wave = K-quarter

  const int bid     = blockIdx.x;
  const int cluster = bid & 7;
  const int j       = bid >> 3;       // 0..31 col-group within cluster
  const int cb      = cluster * BB;   // global batch base
  unsigned* cnt     = flags + cluster;

  // ---- persistent register weights: B-fragments, n = lane&15 -> gate row ----
  short8 wf1[4][5];   // layer1: K=640 -> 20 K-steps, 5 per wave, x4 gates
  short8 wf2[4][8];   // layer2: K=1024 -> 32 K-steps, 8 per wave, x4 gates
  #pragma unroll
  for (int g = 0; g < 4; ++g) {
    const int gr = g * HDIM + j * COLS + lm;
    #pragma unroll
    for (int sl = 0; sl < 5; ++sl) {
      const int k0 = (kq * 5 + sl) * 32 + 8 * lq;          // 0..639
      const float* src = (k0 < DIN) ? (Wih1 + (size_t)gr * DIN + k0)
                                    : (Whh1 + (size_t)gr * HDIM + (k0 - DIN));
      wf1[g][sl] = pack8(*(const float4*)src, *(const float4*)(src + 4));
    }
    #pragma unroll
    for (int sl = 0; sl < 8; ++sl) {
      const int k0 = (kq * 8 + sl) * 32 + 8 * lq;          // 0..1023
      const float* src = (k0 < HDIM) ? (Wih2 + (size_t)gr * HDIM + k0)
                                     : (Whh2 + (size_t)gr * HDIM + (k0 - HDIM));
      wf2[g][sl] = pack8(*(const float4*)src, *(const float4*)(src + 4));
    }
  }
  if (tid < 64) {
    const int g = tid >> 4, nn = tid & 15;
    const int gr = g * HDIM + j * COLS + nn;
    bias1s[tid] = bih1[gr] + bhh1[gr];
    bias2s[tid] = bih2[gr] + bhh2[gr];
  }

  // pickup: thread = (batch row pm, col pnn); owns c1,c2 across all steps
  const int pm = tid >> 4, pnn = tid & 15;
  float c1 = 0.f, c2 = 0.f;

  for (int it = 0; it <= TSEQ; ++it) {
    // ---- stage x_t (peer-independent; overlaps the wait) ----
    if (it < TSEQ) {
      const int row = tid >> 4, kc = tid & 15;
      const float* xp = x + ((size_t)(cb + row) * TSEQ + it) * DIN + kc * 8;
      *(short8*)(&xs[SWZ(row, row * DIN + kc * 8)]) =
          pack8(*(const float4*)xp, *(const float4*)(xp + 4));
    }

    // ---- barrier: all cluster blocks published iteration it-1 ----
    if (it > 0) {
      if (tid == 0) {
        const unsigned thr = (unsigned)(NJ * it);
        while (__hip_atomic_load(cnt, __ATOMIC_RELAXED, SCOPE_AGENT) < thr)
          __builtin_amdgcn_s_sleep(1);
      }
      __syncthreads();
    }

    // ---- stage h slabs via cache-bypassing loads ----
    const unsigned short* h1r =
        buf1 + (size_t)(((it + 1) & 1) * NCL + cluster) * BB * HDIM;  // h1_{it-1}
    const unsigned short* h2r =
        buf2 + (size_t)((it & 1) * NCL + cluster) * BB * HDIM;        // h2_{it-2}
    {
      unsigned long long t[8];
      #pragma unroll
      for (int ci = 0; ci < 4; ++ci) {
        const int c = ci * 256 + tid;
        const int row = c >> 6, kc = c & 63;
        const unsigned long long* s =
            (const unsigned long long*)(h1r + (size_t)row * HDIM + kc * 8);
        t[2 * ci]     = __hip_atomic_load(s,     __ATOMIC_RELAXED, SCOPE_AGENT);
        t[2 * ci + 1] = __hip_atomic_load(s + 1, __ATOMIC_RELAXED, SCOPE_AGENT);
      }
      #pragma unroll
      for (int ci = 0; ci < 4; ++ci) {
        const int c = ci * 256 + tid;
        const int row = c >> 6, kc = c & 63;
        unsigned long long* d =
            (unsigned long long*)&h1s[SWZ(row, row * HDIM + kc * 8)];
        d[0] = t[2 * ci]; d[1] = t[2 * ci + 1];
      }
      #pragma unroll
      for (int ci = 0; ci < 4; ++ci) {
        const int c = ci * 256 + tid;
        const int row = c >> 6, kc = c & 63;
        const unsigned long long* s =
            (const unsigned long long*)(h2r + (size_t)row * HDIM + kc * 8);
        t[2 * ci]     = __hip_atomic_load(s,     __ATOMIC_RELAXED, SCOPE_AGENT);
        t[2 * ci + 1] = __hip_atomic_load(s + 1, __ATOMIC_RELAXED, SCOPE_AGENT);
      }
      #pragma unroll
      for (int ci = 0; ci < 4; ++ci) {
        const int c = ci * 256 + tid;
        const int row = c >> 6, kc = c & 63;
        unsigned long long* d =
            (unsigned long long*)&h2s[SWZ(row, row * HDIM + kc * 8)];
        d[0] = t[2 * ci]; d[1] = t[2 * ci + 1];
      }
    }
    __syncthreads();

    // ---- MFMA: wave kq does its K-quarter, all 4 gate N-tiles ----
    f32x4 z = {0.f, 0.f, 0.f, 0.f};
    f32x4 acc1[4] = {z, z, z, z};
    f32x4 acc2[4] = {z, z, z, z};
    if (it < TSEQ) {
      #pragma unroll
      for (int sl = 0; sl < 5; ++sl) {
        const int s = kq * 5 + sl;       // K = [x(4) | h1(16)] K-steps
        short8 a;
        if (s < 4)
          a = *(const short8*)(&xs[SWZ(lm, lm * DIN + s * 32 + 8 * lq)]);
        else
          a = *(const short8*)(&h1s[SWZ(lm, lm * HDIM + (s - 4) * 32 + 8 * lq)]);
        #pragma unroll
        for (int g = 0; g < 4; ++g) acc1[g] = mfma16(a, wf1[g][sl], acc1[g]);
      }
    }
    if (it >= 1) {
      #pragma unroll
      for (int sl = 0; sl < 8; ++sl) {
        const int s2 = kq * 8 + sl;      // K = [out1(16) | h2(16)] K-steps
        short8 a;
        if (s2 < 16)
          a = *(const short8*)(&h1s[SWZ(lm, lm * HDIM + s2 * 32 + 8 * lq)]);
        else
          a = *(const short8*)(&h2s[SWZ(lm, lm * HDIM + (s2 - 16) * 32 + 8 * lq)]);
        #pragma unroll
        for (int g = 0; g < 4; ++g) acc2[g] = mfma16(a, wf2[g][sl], acc2[g]);
      }
    }
    // C layout: col = lane&15 (gate row), row = lq*4+r (batch row)
    if (it < TSEQ) {
      #pragma unroll
      for (int g = 0; g < 4; ++g)
        #pragma unroll
        for (int r = 0; r < 4; ++r)
          red1[(kq * 16 + lq * 4 + r) * 66 + g * 16 + lm] = acc1[g][r];
    }
    if (it >= 1) {
      #pragma unroll
      for (int g = 0; g < 4; ++g)
        #pragma unroll
        for (int r = 0; r < 4; ++r)
          red2[(kq * 16 + lq * 4 + r) * 66 + g * 16 + lm] = acc2[g][r];
    }
    __syncthreads();

    // ---- pickup: K-quarter reduce + gates + state + publish ----
    if (it < TSEQ) {
      float p[4];
      #pragma unroll
      for (int g = 0; g < 4; ++g) {
        float v = bias1s[g * 16 + pnn];
        #pragma unroll
        for (int q = 0; q < 4; ++q) v += red1[(q * 16 + pm) * 66 + g * 16 + pnn];
        p[g] = v;
      }
      const float i_ = sigf(p[0]), f_ = sigf(p[1]);
      const float g_ = tanh_(p[2]), o_ = sigf(p[3]);
      c1 = f_ * c1 + i_ * g_;
      const float h1v = o_ * tanh_(c1);
      unsigned short* w = buf1 + (size_t)((it & 1) * NCL + cluster) * BB * HDIM;
      __hip_atomic_store(&w[pm * HDIM + j * COLS + pnn], f2bf(h1v),
                         __ATOMIC_RELAXED, SCOPE_AGENT);
    }
    if (it >= 1) {
      float p[4];
      #pragma unroll
      for (int g = 0; g < 4; ++g) {
        float v = bias2s[g * 16 + pnn];
        #pragma unroll
        for (int q = 0; q < 4; ++q) v += red2[(q * 16 + pm) * 66 + g * 16 + pnn];
        p[g] = v;
      }
      const float i_ = sigf(p[0]), f_ = sigf(p[1]);
      const float g_ = tanh_(p[2]), o_ = sigf(p[3]);
      c2 = f_ * c2 + i_ * g_;
      const float h2v = o_ * tanh_(c2);
      if (it < TSEQ) {
        unsigned short* w =
            buf2 + (size_t)(((it + 1) & 1) * NCL + cluster) * BB * HDIM;
        __hip_atomic_store(&w[pm * HDIM + j * COLS + pnn], f2bf(h2v),
                           __ATOMIC_RELAXED, SCOPE_AGENT);
      } else {
        const int b = cb + pm;                       // final states (t = 511)
        out[(size_t)b * HDIM + j * COLS + pnn] = h2v;
        out[(size_t)128 * HDIM + (size_t)b * HDIM + j * COLS + pnn] = c2;
      }
    }
    __syncthreads();   // drains vmcnt: all publishes complete before the add

    // ---- signal: one counter bump per block per step ----
    if (tid == 0 && it < TSEQ)
      __hip_atomic_fetch_add(cnt, 1u, __ATOMIC_RELAXED, SCOPE_AGENT);
  }
}

extern "C" void kernel_launch(void* const* d_in, const int* in_sizes, int n_in,
                              void* d_out, int out_size, void* d_ws, size_t ws_size,
                              hipStream_t stream) {
  const float* x    = (const float*)d_in[0];
  const float* Wih1 = (const float*)d_in[1];
  const float* Whh1 = (const float*)d_in[2];
  const float* bih1 = (const float*)d_in[3];
  const float* bhh1 = (const float*)d_in[4];
  const float* Wih2 = (const float*)d_in[5];
  const float* Whh2 = (const float*)d_in[6];
  const float* bih2 = (const float*)d_in[7];
  const float* bhh2 = (const float*)d_in[8];
  float* out = (float*)d_out;

  const size_t bufElems = (size_t)2 * NCL * BB * HDIM;   // 131072 ushorts each
  unsigned short* buf1 = (unsigned short*)d_ws;
  unsigned short* buf2 = buf1 + bufElems;
  unsigned* flags = (unsigned*)(buf2 + bufElems);

  const int nzero = (int)((bufElems * 2 * 2 + NCL * 4) / 4);   // u32 words
  zero_ws<<<(nzero + 255) / 256, 256, 0, stream>>>((unsigned*)d_ws, nzero);
  lstm_persist<<<256, 256, 0, stream>>>(x, Wih1, Whh1, bih1, bhh1,
                                        Wih2, Whh2, bih2, bhh2,
                                        out, buf1, buf2, flags);
}